// Round 1
// baseline (392.540 us; speedup 1.0000x reference)
//
#include <hip/hip_runtime.h>

#define ND 64
#define NPAIR 6

typedef short bf16x8 __attribute__((ext_vector_type(8)));
typedef float floatx4 __attribute__((ext_vector_type(4)));

static constexpr int SPB  = 8;             // samples per block
static constexpr int ROWS = SPB * NPAIR;   // 48 M-rows per block
static constexpr int ASTR = 200;           // halfwords per A row (192 + 8 pad; 400B, 16B-aligned, bank-spread)

__device__ __forceinline__ unsigned short f2bf(float f) {
    unsigned u = __builtin_bit_cast(unsigned, f);
    u += 0x7FFFu + ((u >> 16) & 1u);       // round-to-nearest-even (no NaN inputs)
    return (unsigned short)(u >> 16);
}
__device__ __forceinline__ unsigned f2bf2(float lo, float hi) {
    return (unsigned)f2bf(lo) | ((unsigned)f2bf(hi) << 16);
}

// Repack W1..3 [o][i][k] fp32 -> bf16 B-operand layout P[L][n=o][j], j<128: (i=j>>1,k=j&1), j>=128: (i=j-128,k=2)
__global__ void repack_w(const float* __restrict__ W1, const float* __restrict__ W2,
                         const float* __restrict__ W3, unsigned short* __restrict__ P) {
    int idx = blockIdx.x * 256 + threadIdx.x;
    if (idx >= 3 * 64 * 192) return;
    int j = idx % 192;
    int n = (idx / 192) % 64;
    int L = idx / (192 * 64);
    const float* W = (L == 0) ? W1 : (L == 1) ? W2 : W3;
    float v = (j < 128) ? W[n * 192 + (j >> 1) * 3 + (j & 1)]
                        : W[n * 192 + (j - 128) * 3 + 2];
    P[idx] = f2bf(v);
}

__global__ __launch_bounds__(256, 7) void dijet_main(
    const float* __restrict__ x, const float* __restrict__ d,
    const float* __restrict__ b1, const float* __restrict__ b2,
    const float* __restrict__ b3, const unsigned short* __restrict__ Wp,
    float* __restrict__ out)
{
    // A: [row][j] bf16, j<128 x-part, j>=128 d-part (updated per layer). 19200 B.
    // At the final epilogue A is dead; reused as Ct (48*64 fp32 = 12288 B).
    __shared__ __align__(16) unsigned short A[ROWS * ASTR];
    float* Ct = (float*)A;

    const int t  = threadIdx.x;
    const int b0 = blockIdx.x * SPB;

    // ---- stage d first (kept in registers for the residual): 8 samples x 384 floats = 1536 float2
    float2 dres[6];
    {
        const float2* d2 = (const float2*)(d + (size_t)b0 * (ND * NPAIR));
        #pragma unroll
        for (int m = 0; m < 6; ++m) dres[m] = d2[m * 256 + t];
    }
    // ---- stage x: 8 samples x 768 floats = 1536 float4; coalesced; convert + scatter to A x-part
    {
        const float4* x4 = (const float4*)(x + (size_t)b0 * (ND * 12));
        float4 v[6];
        #pragma unroll
        for (int m = 0; m < 6; ++m) v[m] = x4[m * 256 + t];
        unsigned* A32 = (unsigned*)A;
        #pragma unroll
        for (int m = 0; m < 6; ++m) {
            int idx = m * 256 + t;                // 0..1535
            int b   = idx / 192;                  // 192 float4 per sample
            int rem = idx - b * 192;
            int i   = rem / 3;                    // channel
            int c0  = (rem - i * 3) * 4;          // 0,4,8
            int row0 = b * 6 + (c0 >> 1);         // slot = c/2
            A32[row0 * (ASTR / 2) + i]       = f2bf2(v[m].x, v[m].y);  // j = 2i, 2i+1
            A32[(row0 + 1) * (ASTR / 2) + i] = f2bf2(v[m].z, v[m].w);
        }
    }
    // ---- scatter d to A d-part: each float2 = same i, slots (s,s+1)
    {
        #pragma unroll
        for (int m = 0; m < 6; ++m) {
            int idx = m * 256 + t;                // 0..1535
            int e   = idx * 2;
            int b   = e / 384;
            int rem = e - b * 384;
            int i   = rem / 6;
            int s   = rem - i * 6;                // even
            int row = b * 6 + s;
            A[row * ASTR + 128 + i]       = f2bf(dres[m].x);
            A[(row + 1) * ASTR + 128 + i] = f2bf(dres[m].y);
        }
    }
    __syncthreads();

    const int wave = t >> 6;
    const int lane = t & 63;
    const int l15  = lane & 15;
    const int quad = lane >> 4;
    const int nbase = wave * 16;                  // each wave: all 48 rows x 16 cols

    #pragma unroll
    for (int L = 0; L < 3; ++L) {
        const float* bL = (L == 0) ? b1 : (L == 1) ? b2 : b3;
        const unsigned short* WL = Wp + L * (64 * 192);

        // B fragments for this wave's 16 output cols: 6 k-steps, from L2-resident packed weights
        bf16x8 Bf[6];
        #pragma unroll
        for (int kk = 0; kk < 6; ++kk)
            Bf[kk] = *(const bf16x8*)(WL + (nbase + l15) * 192 + kk * 32 + quad * 8);
        float bias = bL[nbase + l15];

        floatx4 acc[3] = {};
        #pragma unroll
        for (int kk = 0; kk < 6; ++kk) {
            #pragma unroll
            for (int mt = 0; mt < 3; ++mt) {
                bf16x8 Af = *(const bf16x8*)(A + (mt * 16 + l15) * ASTR + kk * 32 + quad * 8);
                acc[mt] = __builtin_amdgcn_mfma_f32_16x16x32_bf16(Af, Bf[kk], acc[mt], 0, 0, 0);
            }
        }

        const int o = nbase + l15;
        if (L < 2) {
            __syncthreads();   // everyone done reading old d-part
            #pragma unroll
            for (int mt = 0; mt < 3; ++mt) {
                #pragma unroll
                for (int r = 0; r < 4; ++r) {
                    int row = mt * 16 + quad * 4 + r;   // C/D: col=lane&15, row=quad*4+reg
                    float v = acc[mt][r] + bias;
                    v = v > 0.f ? v : 0.f;
                    A[row * ASTR + 128 + o] = f2bf(v);
                }
            }
            __syncthreads();   // new d visible before next layer's reads
        } else {
            __syncthreads();   // all waves done reading A; safe to overlay Ct
            // transpose C (fp32, + bias) into [b][o*6+s] layout over A's storage
            #pragma unroll
            for (int mt = 0; mt < 3; ++mt) {
                #pragma unroll
                for (int r = 0; r < 4; ++r) {
                    int row = mt * 16 + quad * 4 + r;
                    int bl  = row / 6;
                    int s   = row - bl * 6;
                    Ct[bl * (ND * NPAIR) + o * NPAIR + s] = acc[mt][r] + bias;
                }
            }
            __syncthreads();
            // coalesced float2 stores fused with register-resident residual
            float2* out2 = (float2*)(out + (size_t)b0 * (ND * NPAIR));
            const float2* Ct2 = (const float2*)Ct;
            #pragma unroll
            for (int m = 0; m < 6; ++m) {
                int idx = m * 256 + t;               // 0..1535
                float2 c = Ct2[idx];
                float2 r;
                r.x = c.x + dres[m].x; r.x = r.x > 0.f ? r.x : 0.f;
                r.y = c.y + dres[m].y; r.y = r.y > 0.f ? r.y : 0.f;
                out2[idx] = r;
            }
        }
    }
}

extern "C" void kernel_launch(void* const* d_in, const int* in_sizes, int n_in,
                              void* d_out, int out_size, void* d_ws, size_t ws_size,
                              hipStream_t stream)
{
    const float* x  = (const float*)d_in[0];
    const float* dd = (const float*)d_in[1];
    const float* W1 = (const float*)d_in[2];
    const float* b1 = (const float*)d_in[3];
    const float* W2 = (const float*)d_in[4];
    const float* b2 = (const float*)d_in[5];
    const float* W3 = (const float*)d_in[6];
    const float* b3 = (const float*)d_in[7];
    float* out = (float*)d_out;
    unsigned short* Wp = (unsigned short*)d_ws;   // 3*64*192*2 = 73728 B

    int n = in_sizes[0] / (ND * 12);              // 65536

    repack_w<<<144, 256, 0, stream>>>(W1, W2, W3, Wp);
    dijet_main<<<n / SPB, 256, 0, stream>>>(x, dd, b1, b2, b3, Wp, out);
}